// Round 9
// baseline (187.105 us; speedup 1.0000x reference)
//
#include <hip/hip_runtime.h>
#include <hip/hip_bf16.h>

#define NBLK  50000
#define NATOM 400000
#define NEDGE 800000
#define NBS   1563            // ceil(400000/256)

typedef __bf16 bf16x8 __attribute__((ext_vector_type(8)));
typedef float  f32x4  __attribute__((ext_vector_type(4)));

// ---- workspace layout (bytes); WS_NEED = proven 18,403,840 ----
#define START_OFF 0UL          // int32[400001]: counts -> exclusive offsets (+total)
#define CUR_OFF   1600016UL    // int32[400000]: cursors; REUSED as EW1 f32[100][128]
#define BS_OFF    3200016UL    // int32[1563]
#define REC_OFF   3206288UL    // u16 [800000]: per-edge pair ids, CSR by dst atom
#define T_OFF     4806288UL    // f32 [500][128]: msg table; REWRITTEN to TW1 = T@W1
#define POS_OFF   5062288UL    // bf16[1024][128] sinusoid table
#define G2T_OFF   5357200UL    // bf16[128][128] gine_w2^T
#define M0T_OFF   5389968UL    // bf16[128][384] mlp_w0^T
#define M1T_OFF   5488272UL    // bf16[128][128] mlp_w1^T
#define M2T_OFF   5521040UL    // bf16[128][128] mlp_w2^T
#define GM_OFF    5553808UL    // u8 [50000] canonical generate_mask
#define FLAG_OFF  5603808UL    // int32 dtype-sniff flag
#define WS_NEED   18403840UL

#define MFMA(a,b,c) __builtin_amdgcn_mfma_f32_16x16x32_bf16((a),(b),(c),0,0,0)

__device__ inline f32x4 splat4(float v){ f32x4 r; r[0]=v; r[1]=v; r[2]=v; r[3]=v; return r; }
__device__ inline float scrub(float v){ return (v==v && v<1e30f && v>-1e30f) ? v : 0.f; }

// ---------------- dtype sniff for generate_mask (1 block) ----------------
__global__ void k_sniff(const void* gm_raw, char* ws) {
  __shared__ int big;
  if (threadIdx.x == 0) big = 0;
  __syncthreads();
  const unsigned* gw = (const unsigned*)gm_raw;
  for (int i = threadIdx.x; i < 12500; i += 256)
    if (gw[i] > 1u) big = 1;
  __syncthreads();
  if (threadIdx.x == 0) *(int*)(ws + FLAG_OFF) = big;
}

// ------------- prep1: msg table T, sinusoid, W^T (f32->bf16), gm canon ----------
__global__ void k_prep1(const float* atom_embed, const float* bond_embed,
                        const float* g2, const float* m0, const float* m1,
                        const float* m2, const void* gm_raw, char* ws) {
  int b = blockIdx.x, t = threadIdx.x;
  if (b < 100) {                       // T[a*5+bond][c] = relu(ae + be), f32
    float ae = atom_embed[b*128 + t];
    float* T = (float*)(ws + T_OFF);
    for (int bo = 0; bo < 5; ++bo) {
      float v = ae + bond_embed[bo*128 + t];
      T[(b*5 + bo)*128 + t] = v > 0.f ? v : 0.f;
    }
  } else if (b < 1124) {               // sinusoidal table, bf16, fast-math
    int p = b - 100;
    __bf16* P = (__bf16*)(ws + POS_OFF);
    int c = t & 63;
    float invf = exp2f((float)c * -0.20762050593046012f);  // 10000^(-c/64)
    float ang = (float)p * invf;
    float v = (t < 64) ? __sinf(ang) : __cosf(ang);
    P[p*128 + t] = (__bf16)v;
  } else if (b < 1172) {               // weight transposes f32 -> bf16 [n][k]
    int wb = b - 1124;
    const float* src; __bf16* dst; int K; int r0;
    if (wb < 8)       { src = g2; dst = (__bf16*)(ws + G2T_OFF); K = 128; r0 = wb*16; }
    else if (wb < 32) { src = m0; dst = (__bf16*)(ws + M0T_OFF); K = 384; r0 = (wb-8)*16; }
    else if (wb < 40) { src = m1; dst = (__bf16*)(ws + M1T_OFF); K = 128; r0 = (wb-32)*16; }
    else              { src = m2; dst = (__bf16*)(ws + M2T_OFF); K = 128; r0 = (wb-40)*16; }
    for (int rr = 0; rr < 16; ++rr) {
      int r = r0 + rr;
      dst[t*K + r] = (__bf16)src[r*128 + t];
    }
  } else {                             // gm canon: 50 blocks x 1000 elems
    int anyBig = *(const int*)(ws + FLAG_OFF);
    int base = (b - 1172) * 1000;
    unsigned char* gu = (unsigned char*)(ws + GM_OFF);
    if (anyBig) {
      const unsigned char* gb = (const unsigned char*)gm_raw;
      for (int i = t; i < 1000; i += 128) gu[base+i] = gb[base+i] ? 1 : 0;
    } else {
      const int* gi = (const int*)gm_raw;
      for (int i = t; i < 1000; i += 128) gu[base+i] = gi[base+i] ? 1 : 0;
    }
  }
}

// ------- prep2: EW1 = emb@W1+b1 (->CUR region), TW1 = T@W1 (in place over T) -----
__global__ void k_prep2(const float* atom_embed, const float* g1, const float* gb1,
                        char* ws) {
  int b = blockIdx.x, t = threadIdx.x;   // t = output col
  float s0 = 0.f, s1 = 0.f, s2 = 0.f, s3 = 0.f;
  const float* row = (b < 100) ? (atom_embed + b*128) : ((float*)(ws + T_OFF) + (b-100)*128);
  #pragma unroll 4
  for (int k = 0; k < 128; k += 4) {
    s0 += row[k+0] * g1[(k+0)*128 + t];
    s1 += row[k+1] * g1[(k+1)*128 + t];
    s2 += row[k+2] * g1[(k+2)*128 + t];
    s3 += row[k+3] * g1[(k+3)*128 + t];
  }
  float s = (s0 + s1) + (s2 + s3);
  if (b < 100) {
    ((float*)(ws + CUR_OFF))[b*128 + t] = s + gb1[t];
  } else {
    __syncthreads();                     // all reads of row done before overwrite
    ((float*)(ws + T_OFF))[(b-100)*128 + t] = s;   // bias enters via EW1
  }
}

// ---------------- count valid in-edges per dst atom ----------------
__global__ void k_count(const int* __restrict__ bonds, char* ws) {
  int e = blockIdx.x*256 + threadIdx.x;
  if (e >= NEDGE) return;
  const unsigned char* gm = (const unsigned char*)(ws + GM_OFF);
  int src = bonds[e*3], dst = bonds[e*3+1];
  if (gm[src >> 3] | gm[dst >> 3]) return;
  atomicAdd((int*)(ws + START_OFF) + dst, 1);
}

// ---------------- exclusive scan over 400000 counts (3 kernels) ----------------
__global__ void k_scan1(char* ws) {
  __shared__ int s[256];
  int b = blockIdx.x, t = threadIdx.x, i = b*256 + t;
  int* cnt = (int*)(ws + START_OFF);
  int v = (i < NATOM) ? cnt[i] : 0;
  s[t] = v; __syncthreads();
  for (int d = 1; d < 256; d <<= 1) {
    int x = (t >= d) ? s[t-d] : 0;
    __syncthreads(); s[t] += x; __syncthreads();
  }
  if (i < NATOM) cnt[i] = s[t] - v;
  if (t == 255) ((int*)(ws + BS_OFF))[b] = s[255];
}
__global__ void k_scan2(char* ws) {
  __shared__ int s[256]; __shared__ int carry;
  int t = threadIdx.x;
  int* bs = (int*)(ws + BS_OFF);
  if (t == 0) carry = 0;
  __syncthreads();
  for (int c = 0; c < 7; ++c) {
    int i = c*256 + t;
    int v = (i < NBS) ? bs[i] : 0;
    s[t] = v; __syncthreads();
    for (int d = 1; d < 256; d <<= 1) {
      int x = (t >= d) ? s[t-d] : 0;
      __syncthreads(); s[t] += x; __syncthreads();
    }
    int excl = s[t] - v + carry;
    if (i < NBS) bs[i] = excl;
    int tot = s[255]; __syncthreads();
    if (t == 0) carry += tot;
    __syncthreads();
  }
  if (t == 0) ((int*)(ws + START_OFF))[NATOM] = carry;
}
__global__ void k_scan3(char* ws) {
  int b = blockIdx.x, i = b*256 + threadIdx.x;
  if (i >= NATOM) return;
  int* start = (int*)(ws + START_OFF);
  int v = start[i] + ((int*)(ws + BS_OFF))[b];
  start[i] = v;
  ((int*)(ws + CUR_OFF))[i] = v;
}

// ---------------- scatter compact records ----------------
__global__ void k_scatter(const int* __restrict__ bonds, const int* __restrict__ A, char* ws) {
  int e = blockIdx.x*256 + threadIdx.x;
  if (e >= NEDGE) return;
  const unsigned char* gm = (const unsigned char*)(ws + GM_OFF);
  int src = bonds[e*3], dst = bonds[e*3+1];
  if (gm[src >> 3] | gm[dst >> 3]) return;
  int slot = atomicAdd((int*)(ws + CUR_OFF) + dst, 1);
  if (slot >= 0 && slot < NEDGE)
    ((unsigned short*)(ws + REC_OFF))[slot] = (unsigned short)(A[src]*5 + bonds[e*3+2]);
}

// ---- 8-wave GEMM core: 64 rows x 128 cols tile, wave quadrant 32rows x 32cols ----
template<int KB>
__device__ inline void gemm8(const char* sm, const int* poff, const __bf16* wt,
                             int wstride, const float* bias, float bscale,
                             int lane, int wave, f32x4 acc[2][2]) {
  const int colA = (wave & 3)*32 + (lane & 15);
  const int rb   = (wave >> 2)*32;
  const int k0   = (lane >> 4) * 8;
  float bb0 = bias[colA] * bscale, bb1 = bias[colA + 16] * bscale;
  #pragma unroll
  for (int m = 0; m < 2; ++m) { acc[m][0] = splat4(bb0); acc[m][1] = splat4(bb1); }
  #pragma unroll
  for (int kb = 0; kb < KB; ++kb) {
    bf16x8 b0 = *(const bf16x8*)(wt + (long)colA*wstride + kb*32 + k0);
    bf16x8 b1 = *(const bf16x8*)(wt + (long)(colA+16)*wstride + kb*32 + k0);
    int base = poff[kb >> 2];
    #pragma unroll
    for (int m = 0; m < 2; ++m) {
      int rA = rb + m*16 + (lane & 15);
      int byte = base + rA*256 + ((((kb & 3)*64) + k0*2) ^ ((rA & 7) << 4));
      bf16x8 a = *(const bf16x8*)(sm + byte);
      acc[m][0] = MFMA(a, b0, acc[m][0]);
      acc[m][1] = MFMA(a, b1, acc[m][1]);
    }
  }
}

__device__ inline void stor8(char* sm, int off, f32x4 acc[2][2],
                             int lane, int wave, bool do_relu) {
  #pragma unroll
  for (int m = 0; m < 2; ++m)
  #pragma unroll
  for (int nf = 0; nf < 2; ++nf)
  #pragma unroll
  for (int r = 0; r < 4; ++r) {
    float v = acc[m][nf][r];
    if (do_relu && v < 0.f) v = 0.f;
    int row = (wave >> 2)*32 + m*16 + (lane >> 4)*4 + r;
    int col = (wave & 3)*32 + nf*16 + (lane & 15);
    int byte = off + row*256 + ((col*2) ^ ((row & 7) << 4));
    *(__bf16*)(sm + byte) = (__bf16)v;
  }
}

// ---- main: stage pos/aa + in-register gather(topo_pre) -> GEMM2 -> GEMM0 -> GEMM1 -> GEMM3 ----
// 512 threads, 64 mols/block. LDS: pos@0, topo@16384, aa@32768; h1@0, h2@16384.
__launch_bounds__(512, 4)
__global__ void k_main(char* ws, const int* __restrict__ A,
                       const int* __restrict__ pos_ids, const int* __restrict__ is_aa,
                       const float* cr, const float* aa_embed, const float* gb2,
                       const float* mb0, const float* mb1, const float* mb2,
                       float* __restrict__ out) {
  __shared__ __align__(16) char sm[49152];
  const int tid = threadIdx.x, lane = tid & 63, wave = tid >> 6;
  const int r0 = blockIdx.x * 64;
  const unsigned char* gm = (const unsigned char*)(ws + GM_OFF);
  const __bf16* pos_tab = (const __bf16*)(ws + POS_OFF);

  // stage pos@0 and aa@32768: 2048 chunks of 16B, 4 iters x 512
  for (int i = 0; i < 4; ++i) {
    int idx = tid + i*512;
    int panel = idx >> 10;              // 0=pos, 1=aa
    int within = idx & 1023;
    int row = within >> 4, c = within & 15;
    int mol = r0 + row;
    bf16x8 v;
    if (mol < NBLK) {
      if (panel == 0) {
        v = *(const bf16x8*)(pos_tab + pos_ids[mol]*128 + c*8);
      } else {
        int corrupt = gm[mol] && (cr[mol] < 0.1f);
        int sel = corrupt ? 0 : is_aa[mol];
        const float* aaP = aa_embed + sel*128 + c*8;
        f32x4 a0 = *(const f32x4*)(aaP);
        f32x4 a1 = *(const f32x4*)(aaP + 4);
        #pragma unroll
        for (int j = 0; j < 4; ++j) { v[j] = (__bf16)a0[j]; v[j+4] = (__bf16)a1[j]; }
      }
    } else {
      #pragma unroll
      for (int j = 0; j < 8; ++j) v[j] = (__bf16)0.f;
    }
    int byte = (panel ? 32768 : 0) + row*256 + ((c*16) ^ ((row & 7) << 4));
    *(bf16x8*)(sm + byte) = v;
  }

  // gather: thread=(mol ml, eighth q: 16 cols). ms4[4]+u4[4] only (32 f32).
  {
    const int ml = tid >> 3, q = tid & 7;
    const int mol = r0 + ml;
    f32x4 ms4[4];
    #pragma unroll
    for (int j = 0; j < 4; ++j) ms4[j] = splat4(0.f);
    if (mol < NBLK && !gm[mol]) {
      const int* start = (const int*)(ws + START_OFF);
      const unsigned short* rec = (const unsigned short*)(ws + REC_OFF);
      const float* EW1 = (const float*)(ws + CUR_OFF);
      const float* TW1 = (const float*)(ws + T_OFF);
      #pragma unroll
      for (int a = 0; a < 8; ++a) {
        int atom = mol*8 + a;
        int aT = A[atom];
        const f32x4* ep = (const f32x4*)(EW1 + aT*128 + q*16);
        f32x4 u0 = ep[0], u1 = ep[1], u2 = ep[2], u3 = ep[3];
        int s0 = start[atom], s1 = start[atom+1];
        if (s0 < 0) s0 = 0;
        if (s1 > NEDGE) s1 = NEDGE;
        for (int s = s0; s < s1; ++s) {
          int p = rec[s];
          if (p >= 500) p = 0;
          const f32x4* tp = (const f32x4*)(TW1 + p*128 + q*16);
          u0 += tp[0]; u1 += tp[1]; u2 += tp[2]; u3 += tp[3];
        }
        #pragma unroll
        for (int k = 0; k < 4; ++k) {
          ms4[0][k] += fmaxf(u0[k], 0.f); ms4[1][k] += fmaxf(u1[k], 0.f);
          ms4[2][k] += fmaxf(u2[k], 0.f); ms4[3][k] += fmaxf(u3[k], 0.f);
        }
      }
    }
    #pragma unroll
    for (int j = 0; j < 2; ++j) {
      bf16x8 o;
      #pragma unroll
      for (int k = 0; k < 4; ++k) {
        o[k]   = (__bf16)ms4[j*2][k];
        o[k+4] = (__bf16)ms4[j*2+1][k];
      }
      int byte = 16384 + ml*256 + (((q*32) + j*16) ^ ((ml & 7) << 4));
      *(bf16x8*)(sm + byte) = o;
    }
  }
  __syncthreads();

  const int p_topo[1] = {16384};
  const int p_x[3]    = {0, 16384, 32768};
  const int p_h1[1]   = {0};
  const int p_h2[1]   = {16384};
  f32x4 acc[2][2];

  // GEMM2: topo = rs8*(topo_pre @ W2 + 8*b2), masked; rewrite topo panel
  gemm8<4>(sm, p_topo, (const __bf16*)(ws + G2T_OFF), 128, gb2, 8.0f, lane, wave, acc);
  __syncthreads();
  {
    const float rs8 = 0.35355339059327373f;
    #pragma unroll
    for (int m = 0; m < 2; ++m)
    #pragma unroll
    for (int nf = 0; nf < 2; ++nf)
    #pragma unroll
    for (int r = 0; r < 4; ++r) {
      int row = (wave >> 2)*32 + m*16 + (lane >> 4)*4 + r;
      int col = (wave & 3)*32 + nf*16 + (lane & 15);
      int mol = r0 + row;
      float v = (mol < NBLK && !gm[mol]) ? scrub(acc[m][nf][r] * rs8) : 0.f;
      int byte = 16384 + row*256 + ((col*2) ^ ((row & 7) << 4));
      *(__bf16*)(sm + byte) = (__bf16)v;
    }
  }
  __syncthreads();

  // GEMM0: x=[pos|topo|aa] (K=384) @ W0 + b0, relu -> h1 @0
  gemm8<12>(sm, p_x, (const __bf16*)(ws + M0T_OFF), 384, mb0, 1.0f, lane, wave, acc);
  __syncthreads();
  stor8(sm, 0, acc, lane, wave, true);
  __syncthreads();

  // GEMM1 -> relu -> h2 @16384 (topo reads finished before previous barriers)
  gemm8<4>(sm, p_h1, (const __bf16*)(ws + M1T_OFF), 128, mb1, 1.0f, lane, wave, acc);
  stor8(sm, 16384, acc, lane, wave, true);
  __syncthreads();

  // GEMM3 -> out
  gemm8<4>(sm, p_h2, (const __bf16*)(ws + M2T_OFF), 128, mb2, 1.0f, lane, wave, acc);
  #pragma unroll
  for (int m = 0; m < 2; ++m)
  #pragma unroll
  for (int nf = 0; nf < 2; ++nf)
  #pragma unroll
  for (int r = 0; r < 4; ++r) {
    int row = (wave >> 2)*32 + m*16 + (lane >> 4)*4 + r;
    int col = (wave & 3)*32 + nf*16 + (lane & 15);
    int mol = r0 + row;
    if (mol < NBLK) out[(long)mol*128 + col] = scrub(acc[m][nf][r]);
  }
}

extern "C" void kernel_launch(void* const* d_in, const int* in_sizes, int n_in,
                              void* d_out, int out_size, void* d_ws, size_t ws_size,
                              hipStream_t stream) {
  if (ws_size < WS_NEED) return;   // diagnostic: absmax-fail instead of fault
  const int* A      = (const int*)d_in[0];
  const int* bonds  = (const int*)d_in[1];
  const void* gm    = d_in[3];
  const int* pos    = (const int*)d_in[4];
  const int* isaa   = (const int*)d_in[5];
  const float* cr   = (const float*)d_in[6];
  const float* atom_embed = (const float*)d_in[7];
  const float* bond_embed = (const float*)d_in[8];
  const float* aa_embed   = (const float*)d_in[9];
  const float* g1  = (const float*)d_in[10];
  const float* gb1 = (const float*)d_in[11];
  const float* g2  = (const float*)d_in[12];
  const float* gb2 = (const float*)d_in[13];
  const float* m0  = (const float*)d_in[14];
  const float* mb0 = (const float*)d_in[15];
  const float* m1  = (const float*)d_in[16];
  const float* mb1 = (const float*)d_in[17];
  const float* m2  = (const float*)d_in[18];
  const float* mb2 = (const float*)d_in[19];
  char* ws = (char*)d_ws;

  hipMemsetAsync(ws + START_OFF, 0, (size_t)(NATOM+1)*4, stream);
  k_sniff  <<<1, 256, 0, stream>>>(gm, ws);
  k_prep1  <<<1222, 128, 0, stream>>>(atom_embed, bond_embed, g2, m0, m1, m2, gm, ws);
  k_count  <<<3125, 256, 0, stream>>>(bonds, ws);
  k_scan1  <<<NBS, 256, 0, stream>>>(ws);
  k_scan2  <<<1, 256, 0, stream>>>(ws);
  k_scan3  <<<NBS, 256, 0, stream>>>(ws);
  k_scatter<<<3125, 256, 0, stream>>>(bonds, A, ws);
  k_prep2  <<<600, 128, 0, stream>>>(atom_embed, g1, gb1, ws);   // EW1 -> CUR, TW1 in place
  k_main   <<<(NBLK + 63)/64, 512, 0, stream>>>(ws, A, pos, isaa, cr, aa_embed,
                                                gb2, mb0, mb1, mb2, (float*)d_out);
}

// Round 10
// 175.296 us; speedup vs baseline: 1.0674x; 1.0674x over previous
//
#include <hip/hip_runtime.h>
#include <hip/hip_bf16.h>

#define NBLK  50000
#define NATOM 400000
#define NEDGE 800000
#define NBS   1563            // ceil(400000/256)

typedef __bf16 bf16x8 __attribute__((ext_vector_type(8)));
typedef float  f32x4  __attribute__((ext_vector_type(4)));

// ---- workspace layout (bytes); WS_NEED = proven 18,403,840 ----
#define START_OFF 0UL          // int32[400001]: counts -> exclusive offsets (+total)
#define CUR_OFF   1600016UL    // int32[400000]: cursors; REUSED as EW1 f32[100][128]
#define BS_OFF    3200016UL    // int32[1563]
#define REC_OFF   3206288UL    // u16 [800000]: per-edge pair ids, CSR by dst atom
#define T_OFF     4806288UL    // f32 [500][128]: msg table; REWRITTEN to TW1 = T@W1
#define POS_OFF   5062288UL    // bf16[1024][128] sinusoid table
#define G2T_OFF   5357200UL    // bf16[128][128] gine_w2^T
#define M0T_OFF   5389968UL    // bf16[128][384] mlp_w0^T
#define M1T_OFF   5488272UL    // bf16[128][128] mlp_w1^T
#define M2T_OFF   5521040UL    // bf16[128][128] mlp_w2^T
#define GM_OFF    5553808UL    // u8 [50000] canonical generate_mask
#define FLAG_OFF  5603808UL    // int32 dtype-sniff flag
#define WS_NEED   18403840UL

#define MFMA(a,b,c) __builtin_amdgcn_mfma_f32_16x16x32_bf16((a),(b),(c),0,0,0)

__device__ inline f32x4 splat4(float v){ f32x4 r; r[0]=v; r[1]=v; r[2]=v; r[3]=v; return r; }
__device__ inline float scrub(float v){ return (v==v && v<1e30f && v>-1e30f) ? v : 0.f; }

// ---------------- dtype sniff for generate_mask (1 block) ----------------
__global__ void k_sniff(const void* gm_raw, char* ws) {
  __shared__ int big;
  if (threadIdx.x == 0) big = 0;
  __syncthreads();
  const unsigned* gw = (const unsigned*)gm_raw;
  for (int i = threadIdx.x; i < 12500; i += 256)
    if (gw[i] > 1u) big = 1;
  __syncthreads();
  if (threadIdx.x == 0) *(int*)(ws + FLAG_OFF) = big;
}

// ------------- prep1: msg table T, sinusoid, W^T (f32->bf16), gm canon ----------
__global__ void k_prep1(const float* atom_embed, const float* bond_embed,
                        const float* g2, const float* m0, const float* m1,
                        const float* m2, const void* gm_raw, char* ws) {
  int b = blockIdx.x, t = threadIdx.x;
  if (b < 100) {                       // T[a*5+bond][c] = relu(ae + be), f32
    float ae = atom_embed[b*128 + t];
    float* T = (float*)(ws + T_OFF);
    for (int bo = 0; bo < 5; ++bo) {
      float v = ae + bond_embed[bo*128 + t];
      T[(b*5 + bo)*128 + t] = v > 0.f ? v : 0.f;
    }
  } else if (b < 1124) {               // sinusoidal table, bf16, fast-math
    int p = b - 100;
    __bf16* P = (__bf16*)(ws + POS_OFF);
    int c = t & 63;
    float invf = exp2f((float)c * -0.20762050593046012f);  // 10000^(-c/64)
    float ang = (float)p * invf;
    float v = (t < 64) ? __sinf(ang) : __cosf(ang);
    P[p*128 + t] = (__bf16)v;
  } else if (b < 1172) {               // weight transposes f32 -> bf16 [n][k]
    int wb = b - 1124;
    const float* src; __bf16* dst; int K; int r0;
    if (wb < 8)       { src = g2; dst = (__bf16*)(ws + G2T_OFF); K = 128; r0 = wb*16; }
    else if (wb < 32) { src = m0; dst = (__bf16*)(ws + M0T_OFF); K = 384; r0 = (wb-8)*16; }
    else if (wb < 40) { src = m1; dst = (__bf16*)(ws + M1T_OFF); K = 128; r0 = (wb-32)*16; }
    else              { src = m2; dst = (__bf16*)(ws + M2T_OFF); K = 128; r0 = (wb-40)*16; }
    for (int rr = 0; rr < 16; ++rr) {
      int r = r0 + rr;
      dst[t*K + r] = (__bf16)src[r*128 + t];
    }
  } else {                             // gm canon: 50 blocks x 1000 elems
    int anyBig = *(const int*)(ws + FLAG_OFF);
    int base = (b - 1172) * 1000;
    unsigned char* gu = (unsigned char*)(ws + GM_OFF);
    if (anyBig) {
      const unsigned char* gb = (const unsigned char*)gm_raw;
      for (int i = t; i < 1000; i += 128) gu[base+i] = gb[base+i] ? 1 : 0;
    } else {
      const int* gi = (const int*)gm_raw;
      for (int i = t; i < 1000; i += 128) gu[base+i] = gi[base+i] ? 1 : 0;
    }
  }
}

// ------- prep2: EW1 = emb@W1+b1 (->CUR region), TW1 = T@W1 (in place over T) -----
__global__ void k_prep2(const float* atom_embed, const float* g1, const float* gb1,
                        char* ws) {
  int b = blockIdx.x, t = threadIdx.x;   // t = output col
  float s0 = 0.f, s1 = 0.f, s2 = 0.f, s3 = 0.f;
  const float* row = (b < 100) ? (atom_embed + b*128) : ((float*)(ws + T_OFF) + (b-100)*128);
  #pragma unroll 4
  for (int k = 0; k < 128; k += 4) {
    s0 += row[k+0] * g1[(k+0)*128 + t];
    s1 += row[k+1] * g1[(k+1)*128 + t];
    s2 += row[k+2] * g1[(k+2)*128 + t];
    s3 += row[k+3] * g1[(k+3)*128 + t];
  }
  float s = (s0 + s1) + (s2 + s3);
  if (b < 100) {
    ((float*)(ws + CUR_OFF))[b*128 + t] = s + gb1[t];
  } else {
    __syncthreads();                     // all reads of row done before overwrite
    ((float*)(ws + T_OFF))[(b-100)*128 + t] = s;   // bias enters via EW1
  }
}

// ---------------- count valid in-edges per dst atom ----------------
__global__ void k_count(const int* __restrict__ bonds, char* ws) {
  int e = blockIdx.x*256 + threadIdx.x;
  if (e >= NEDGE) return;
  const unsigned char* gm = (const unsigned char*)(ws + GM_OFF);
  int src = bonds[e*3], dst = bonds[e*3+1];
  if (gm[src >> 3] | gm[dst >> 3]) return;
  atomicAdd((int*)(ws + START_OFF) + dst, 1);
}

// ---------------- exclusive scan over 400000 counts (3 kernels) ----------------
__global__ void k_scan1(char* ws) {
  __shared__ int s[256];
  int b = blockIdx.x, t = threadIdx.x, i = b*256 + t;
  int* cnt = (int*)(ws + START_OFF);
  int v = (i < NATOM) ? cnt[i] : 0;
  s[t] = v; __syncthreads();
  for (int d = 1; d < 256; d <<= 1) {
    int x = (t >= d) ? s[t-d] : 0;
    __syncthreads(); s[t] += x; __syncthreads();
  }
  if (i < NATOM) cnt[i] = s[t] - v;
  if (t == 255) ((int*)(ws + BS_OFF))[b] = s[255];
}
__global__ void k_scan2(char* ws) {
  __shared__ int s[256]; __shared__ int carry;
  int t = threadIdx.x;
  int* bs = (int*)(ws + BS_OFF);
  if (t == 0) carry = 0;
  __syncthreads();
  for (int c = 0; c < 7; ++c) {
    int i = c*256 + t;
    int v = (i < NBS) ? bs[i] : 0;
    s[t] = v; __syncthreads();
    for (int d = 1; d < 256; d <<= 1) {
      int x = (t >= d) ? s[t-d] : 0;
      __syncthreads(); s[t] += x; __syncthreads();
    }
    int excl = s[t] - v + carry;
    if (i < NBS) bs[i] = excl;
    int tot = s[255]; __syncthreads();
    if (t == 0) carry += tot;
    __syncthreads();
  }
  if (t == 0) ((int*)(ws + START_OFF))[NATOM] = carry;
}
__global__ void k_scan3(char* ws) {
  int b = blockIdx.x, i = b*256 + threadIdx.x;
  if (i >= NATOM) return;
  int* start = (int*)(ws + START_OFF);
  int v = start[i] + ((int*)(ws + BS_OFF))[b];
  start[i] = v;
  ((int*)(ws + CUR_OFF))[i] = v;
}

// ---------------- scatter compact records ----------------
__global__ void k_scatter(const int* __restrict__ bonds, const int* __restrict__ A, char* ws) {
  int e = blockIdx.x*256 + threadIdx.x;
  if (e >= NEDGE) return;
  const unsigned char* gm = (const unsigned char*)(ws + GM_OFF);
  int src = bonds[e*3], dst = bonds[e*3+1];
  if (gm[src >> 3] | gm[dst >> 3]) return;
  int slot = atomicAdd((int*)(ws + CUR_OFF) + dst, 1);
  if (slot >= 0 && slot < NEDGE)
    ((unsigned short*)(ws + REC_OFF))[slot] = (unsigned short)(A[src]*5 + bonds[e*3+2]);
}

// ---- 8-wave GEMM core: 64 rows x 128 cols tile, wave quadrant 32rows x 32cols ----
template<int KB>
__device__ inline void gemm8(const char* sm, const int* poff, const __bf16* wt,
                             int wstride, const float* bias, float bscale,
                             int lane, int wave, f32x4 acc[2][2]) {
  const int colA = (wave & 3)*32 + (lane & 15);
  const int rb   = (wave >> 2)*32;
  const int k0   = (lane >> 4) * 8;
  float bb0 = bias[colA] * bscale, bb1 = bias[colA + 16] * bscale;
  #pragma unroll
  for (int m = 0; m < 2; ++m) { acc[m][0] = splat4(bb0); acc[m][1] = splat4(bb1); }
  #pragma unroll
  for (int kb = 0; kb < KB; ++kb) {
    bf16x8 b0 = *(const bf16x8*)(wt + (long)colA*wstride + kb*32 + k0);
    bf16x8 b1 = *(const bf16x8*)(wt + (long)(colA+16)*wstride + kb*32 + k0);
    int base = poff[kb >> 2];
    #pragma unroll
    for (int m = 0; m < 2; ++m) {
      int rA = rb + m*16 + (lane & 15);
      int byte = base + rA*256 + ((((kb & 3)*64) + k0*2) ^ ((rA & 7) << 4));
      bf16x8 a = *(const bf16x8*)(sm + byte);
      acc[m][0] = MFMA(a, b0, acc[m][0]);
      acc[m][1] = MFMA(a, b1, acc[m][1]);
    }
  }
}

__device__ inline void stor8(char* sm, int off, f32x4 acc[2][2],
                             int lane, int wave, bool do_relu) {
  #pragma unroll
  for (int m = 0; m < 2; ++m)
  #pragma unroll
  for (int nf = 0; nf < 2; ++nf)
  #pragma unroll
  for (int r = 0; r < 4; ++r) {
    float v = acc[m][nf][r];
    if (do_relu && v < 0.f) v = 0.f;
    int row = (wave >> 2)*32 + m*16 + (lane >> 4)*4 + r;
    int col = (wave & 3)*32 + nf*16 + (lane & 15);
    int byte = off + row*256 + ((col*2) ^ ((row & 7) << 4));
    *(__bf16*)(sm + byte) = (__bf16)v;
  }
}

// ---- main: stage pos/aa + in-register gather(topo_pre) -> GEMM2 -> GEMM0 -> GEMM1 -> GEMM3 ----
// 512 threads, 64 mols/block. LDS: pos@0, topo@16384, aa@32768; h1@0, h2@16384.
// launch_bounds(512,2): 16 waves/CU -> 128-VGPR budget (32 waves/CU capped us at 64 and spilled, r9)
__launch_bounds__(512, 2)
__global__ void k_main(char* ws, const int* __restrict__ A,
                       const int* __restrict__ pos_ids, const int* __restrict__ is_aa,
                       const float* cr, const float* aa_embed, const float* gb2,
                       const float* mb0, const float* mb1, const float* mb2,
                       float* __restrict__ out) {
  __shared__ __align__(16) char sm[49152];
  const int tid = threadIdx.x, lane = tid & 63, wave = tid >> 6;
  const int r0 = blockIdx.x * 64;
  const unsigned char* gm = (const unsigned char*)(ws + GM_OFF);
  const __bf16* pos_tab = (const __bf16*)(ws + POS_OFF);

  // stage pos@0 and aa@32768: 2048 chunks of 16B, 4 iters x 512
  for (int i = 0; i < 4; ++i) {
    int idx = tid + i*512;
    int panel = idx >> 10;              // 0=pos, 1=aa
    int within = idx & 1023;
    int row = within >> 4, c = within & 15;
    int mol = r0 + row;
    bf16x8 v;
    if (mol < NBLK) {
      if (panel == 0) {
        v = *(const bf16x8*)(pos_tab + pos_ids[mol]*128 + c*8);
      } else {
        int corrupt = gm[mol] && (cr[mol] < 0.1f);
        int sel = corrupt ? 0 : is_aa[mol];
        const float* aaP = aa_embed + sel*128 + c*8;
        f32x4 a0 = *(const f32x4*)(aaP);
        f32x4 a1 = *(const f32x4*)(aaP + 4);
        #pragma unroll
        for (int j = 0; j < 4; ++j) { v[j] = (__bf16)a0[j]; v[j+4] = (__bf16)a1[j]; }
      }
    } else {
      #pragma unroll
      for (int j = 0; j < 8; ++j) v[j] = (__bf16)0.f;
    }
    int byte = (panel ? 32768 : 0) + row*256 + ((c*16) ^ ((row & 7) << 4));
    *(bf16x8*)(sm + byte) = v;
  }

  // gather: thread=(mol ml, eighth q: 16 cols). Vector-prefetched A/start (kills
  // the 16-deep dependent scalar-load chain); u/ms = 32 f32 live.
  {
    const int ml = tid >> 3, q = tid & 7;
    const int mol = r0 + ml;
    f32x4 ms4[4];
    #pragma unroll
    for (int j = 0; j < 4; ++j) ms4[j] = splat4(0.f);
    if (mol < NBLK && !gm[mol]) {
      const int* start = (const int*)(ws + START_OFF);
      const unsigned short* rec = (const unsigned short*)(ws + REC_OFF);
      const float* EW1 = (const float*)(ws + CUR_OFF);
      const float* TW1 = (const float*)(ws + T_OFF);
      int4 aV0 = *(const int4*)(A + mol*8);
      int4 aV1 = *(const int4*)(A + mol*8 + 4);
      int4 sV0 = *(const int4*)(start + mol*8);
      int4 sV1 = *(const int4*)(start + mol*8 + 4);
      int sEnd = start[mol*8 + 8];
      const int aT[8] = {aV0.x, aV0.y, aV0.z, aV0.w, aV1.x, aV1.y, aV1.z, aV1.w};
      const int sa[9] = {sV0.x, sV0.y, sV0.z, sV0.w, sV1.x, sV1.y, sV1.z, sV1.w, sEnd};
      #pragma unroll
      for (int a = 0; a < 8; ++a) {
        const f32x4* ep = (const f32x4*)(EW1 + aT[a]*128 + q*16);
        f32x4 u0 = ep[0], u1 = ep[1], u2 = ep[2], u3 = ep[3];
        int s0 = sa[a], s1 = sa[a+1];
        if (s0 < 0) s0 = 0;
        if (s1 > NEDGE) s1 = NEDGE;
        for (int s = s0; s < s1; ++s) {
          int p = rec[s];
          if (p >= 500) p = 0;
          const f32x4* tp = (const f32x4*)(TW1 + p*128 + q*16);
          u0 += tp[0]; u1 += tp[1]; u2 += tp[2]; u3 += tp[3];
        }
        #pragma unroll
        for (int k = 0; k < 4; ++k) {
          ms4[0][k] += fmaxf(u0[k], 0.f); ms4[1][k] += fmaxf(u1[k], 0.f);
          ms4[2][k] += fmaxf(u2[k], 0.f); ms4[3][k] += fmaxf(u3[k], 0.f);
        }
      }
    }
    #pragma unroll
    for (int j = 0; j < 2; ++j) {
      bf16x8 o;
      #pragma unroll
      for (int k = 0; k < 4; ++k) {
        o[k]   = (__bf16)ms4[j*2][k];
        o[k+4] = (__bf16)ms4[j*2+1][k];
      }
      int byte = 16384 + ml*256 + (((q*32) + j*16) ^ ((ml & 7) << 4));
      *(bf16x8*)(sm + byte) = o;
    }
  }
  __syncthreads();

  const int p_topo[1] = {16384};
  const int p_x[3]    = {0, 16384, 32768};
  const int p_h1[1]   = {0};
  const int p_h2[1]   = {16384};
  f32x4 acc[2][2];

  // GEMM2: topo = rs8*(topo_pre @ W2 + 8*b2), masked; rewrite topo panel
  gemm8<4>(sm, p_topo, (const __bf16*)(ws + G2T_OFF), 128, gb2, 8.0f, lane, wave, acc);
  __syncthreads();
  {
    const float rs8 = 0.35355339059327373f;
    #pragma unroll
    for (int m = 0; m < 2; ++m)
    #pragma unroll
    for (int nf = 0; nf < 2; ++nf)
    #pragma unroll
    for (int r = 0; r < 4; ++r) {
      int row = (wave >> 2)*32 + m*16 + (lane >> 4)*4 + r;
      int col = (wave & 3)*32 + nf*16 + (lane & 15);
      int mol = r0 + row;
      float v = (mol < NBLK && !gm[mol]) ? scrub(acc[m][nf][r] * rs8) : 0.f;
      int byte = 16384 + row*256 + ((col*2) ^ ((row & 7) << 4));
      *(__bf16*)(sm + byte) = (__bf16)v;
    }
  }
  __syncthreads();

  // GEMM0: x=[pos|topo|aa] (K=384) @ W0 + b0, relu -> h1 @0
  gemm8<12>(sm, p_x, (const __bf16*)(ws + M0T_OFF), 384, mb0, 1.0f, lane, wave, acc);
  __syncthreads();
  stor8(sm, 0, acc, lane, wave, true);
  __syncthreads();

  // GEMM1 -> relu -> h2 @16384
  gemm8<4>(sm, p_h1, (const __bf16*)(ws + M1T_OFF), 128, mb1, 1.0f, lane, wave, acc);
  stor8(sm, 16384, acc, lane, wave, true);
  __syncthreads();

  // GEMM3 -> out
  gemm8<4>(sm, p_h2, (const __bf16*)(ws + M2T_OFF), 128, mb2, 1.0f, lane, wave, acc);
  #pragma unroll
  for (int m = 0; m < 2; ++m)
  #pragma unroll
  for (int nf = 0; nf < 2; ++nf)
  #pragma unroll
  for (int r = 0; r < 4; ++r) {
    int row = (wave >> 2)*32 + m*16 + (lane >> 4)*4 + r;
    int col = (wave & 3)*32 + nf*16 + (lane & 15);
    int mol = r0 + row;
    if (mol < NBLK) out[(long)mol*128 + col] = scrub(acc[m][nf][r]);
  }
}

extern "C" void kernel_launch(void* const* d_in, const int* in_sizes, int n_in,
                              void* d_out, int out_size, void* d_ws, size_t ws_size,
                              hipStream_t stream) {
  if (ws_size < WS_NEED) return;   // diagnostic: absmax-fail instead of fault
  const int* A      = (const int*)d_in[0];
  const int* bonds  = (const int*)d_in[1];
  const void* gm    = d_in[3];
  const int* pos    = (const int*)d_in[4];
  const int* isaa   = (const int*)d_in[5];
  const float* cr   = (const float*)d_in[6];
  const float* atom_embed = (const float*)d_in[7];
  const float* bond_embed = (const float*)d_in[8];
  const float* aa_embed   = (const float*)d_in[9];
  const float* g1  = (const float*)d_in[10];
  const float* gb1 = (const float*)d_in[11];
  const float* g2  = (const float*)d_in[12];
  const float* gb2 = (const float*)d_in[13];
  const float* m0  = (const float*)d_in[14];
  const float* mb0 = (const float*)d_in[15];
  const float* m1  = (const float*)d_in[16];
  const float* mb1 = (const float*)d_in[17];
  const float* m2  = (const float*)d_in[18];
  const float* mb2 = (const float*)d_in[19];
  char* ws = (char*)d_ws;

  hipMemsetAsync(ws + START_OFF, 0, (size_t)(NATOM+1)*4, stream);
  k_sniff  <<<1, 256, 0, stream>>>(gm, ws);
  k_prep1  <<<1222, 128, 0, stream>>>(atom_embed, bond_embed, g2, m0, m1, m2, gm, ws);
  k_count  <<<3125, 256, 0, stream>>>(bonds, ws);
  k_scan1  <<<NBS, 256, 0, stream>>>(ws);
  k_scan2  <<<1, 256, 0, stream>>>(ws);
  k_scan3  <<<NBS, 256, 0, stream>>>(ws);
  k_scatter<<<3125, 256, 0, stream>>>(bonds, A, ws);
  k_prep2  <<<600, 128, 0, stream>>>(atom_embed, g1, gb1, ws);   // EW1 -> CUR, TW1 in place
  k_main   <<<(NBLK + 63)/64, 512, 0, stream>>>(ws, A, pos, isaa, cr, aa_embed,
                                                gb2, mb0, mb1, mb2, (float*)d_out);
}

// Round 12
// 154.449 us; speedup vs baseline: 1.2114x; 1.1350x over previous
//
#include <hip/hip_runtime.h>
#include <hip/hip_bf16.h>

#define NBLK  50000
#define NATOM 400000
#define NEDGE 800000
#define NBS   1563            // ceil(400000/256)

typedef __bf16 bf16x8 __attribute__((ext_vector_type(8)));
typedef __bf16 bf16x4 __attribute__((ext_vector_type(4)));
typedef float  f32x4  __attribute__((ext_vector_type(4)));

// ---- workspace layout (bytes); fits proven WS_NEED = 18,403,840 ----
#define START_OFF 0UL          // int32[400001]: counts -> exclusive offsets
#define CUR_OFF   1600016UL    // int32[400000]: cursors; REUSED as EW1 f32[100][128]
#define BS_OFF    3200016UL    // int32[1563]
#define REC_OFF   3206288UL    // u16 [800000]: per-edge pair ids, CSR by dst atom
#define T_OFF     4806288UL    // f32 [500][128]: msg table; REWRITTEN to TW1 = T@W1
#define PW_OFF    5062288UL    // bf16[1024][128]: sinusoid @ W0[0:128]
#define W2T_OFF   5324432UL    // bf16[128][128]: (rs8*W2@W0[128:256])^T  [n][k]
#define M1T_OFF   5357200UL    // bf16[128][128] mlp_w1^T
#define M2T_OFF   5389968UL    // bf16[128][128] mlp_w2^T
#define AAW_OFF   5422736UL    // f32 [4][128]: aa@W0[256:384] + f*8*rs8*(b2@W0[128:256])
#define GM_OFF    5424784UL    // u8 [50000]
#define FLAG_OFF  5474784UL    // int32 sniff flag
#define TOPO_OFF  5474816UL    // bf16[50000][128] topo_pre  (ends 18,274,816)
#define WS_NEED   18403840UL

#define RS8 0.35355339059327373f

#define MFMA(a,b,c) __builtin_amdgcn_mfma_f32_16x16x32_bf16((a),(b),(c),0,0,0)

__device__ inline f32x4 splat4(float v){ f32x4 r; r[0]=v; r[1]=v; r[2]=v; r[3]=v; return r; }
__device__ inline float scrub(float v){ return (v==v && v<1e30f && v>-1e30f) ? v : 0.f; }

// ---------------- dtype sniff for generate_mask (1 block) ----------------
__global__ void k_sniff(const void* gm_raw, char* ws) {
  __shared__ int big;
  if (threadIdx.x == 0) big = 0;
  __syncthreads();
  const unsigned* gw = (const unsigned*)gm_raw;
  for (int i = threadIdx.x; i < 12500; i += 256)
    if (gw[i] > 1u) big = 1;
  __syncthreads();
  if (threadIdx.x == 0) *(int*)(ws + FLAG_OFF) = big;
}

// ------------- prep1: msg table T, M1T/M2T transposes, gm canon ----------
// blocks: [0,100) T, [100,116) transposes, [116,166) gm canon
__global__ void k_prep1(const float* atom_embed, const float* bond_embed,
                        const float* m1, const float* m2, const void* gm_raw, char* ws) {
  int b = blockIdx.x, t = threadIdx.x;
  if (b < 100) {                       // T[a*5+bond][c] = relu(ae + be), f32
    float ae = atom_embed[b*128 + t];
    float* T = (float*)(ws + T_OFF);
    for (int bo = 0; bo < 5; ++bo) {
      float v = ae + bond_embed[bo*128 + t];
      T[(b*5 + bo)*128 + t] = v > 0.f ? v : 0.f;
    }
  } else if (b < 116) {                // weight transposes f32 -> bf16 [n][k]
    int wb = b - 100;
    const float* src; __bf16* dst; int r0;
    if (wb < 8) { src = m1; dst = (__bf16*)(ws + M1T_OFF); r0 = wb*16; }
    else        { src = m2; dst = (__bf16*)(ws + M2T_OFF); r0 = (wb-8)*16; }
    for (int rr = 0; rr < 16; ++rr) {
      int r = r0 + rr;
      dst[t*128 + r] = (__bf16)src[r*128 + t];
    }
  } else {                             // gm canon: 50 blocks x 1000 elems
    int anyBig = *(const int*)(ws + FLAG_OFF);
    int base = (b - 116) * 1000;
    unsigned char* gu = (unsigned char*)(ws + GM_OFF);
    if (anyBig) {
      const unsigned char* gb = (const unsigned char*)gm_raw;
      for (int i = t; i < 1000; i += 128) gu[base+i] = gb[base+i] ? 1 : 0;
    } else {
      const int* gi = (const int*)gm_raw;
      for (int i = t; i < 1000; i += 128) gu[base+i] = gi[base+i] ? 1 : 0;
    }
  }
}

// ------------- prep3: PW, W2T', AAW (pure-input precomputes) ----------
// blocks: [0,1024) PW rows, [1024,1152) W2T rows, [1152,1156) AAW rows
__global__ void k_prep3(const float* m0, const float* g2, const float* gb2,
                        const float* aa_embed, char* ws) {
  int b = blockIdx.x, t = threadIdx.x;
  if (b < 1024) {                      // PW[p][t] = sum_j s(p,j)*W0[j][t], bf16
    __shared__ float s[128];
    int c = t & 63;
    float invf = exp2f((float)c * -0.20762050593046012f);  // 10000^(-c/64)
    float ang = (float)b * invf;
    s[t] = (t < 64) ? __sinf(ang) : __cosf(ang);
    __syncthreads();
    float acc = 0.f;
    #pragma unroll 4
    for (int j = 0; j < 128; ++j) acc += s[j] * m0[j*128 + t];
    ((__bf16*)(ws + PW_OFF))[b*128 + t] = (__bf16)acc;
  } else if (b < 1152) {               // W2T[c][r] = rs8 * sum_j W2[r][j]*W0[128+j][c]
    int r = b - 1024;
    float acc = 0.f;
    #pragma unroll 4
    for (int j = 0; j < 128; ++j) acc += g2[r*128 + j] * m0[(128+j)*128 + t];
    ((__bf16*)(ws + W2T_OFF))[t*128 + r] = (__bf16)(acc * RS8);
  } else {                             // AAW[sf][t], sf = sel + 2*f
    int sf = b - 1152, sel = sf & 1, f = sf >> 1;
    float acc = 0.f;
    #pragma unroll 4
    for (int j = 0; j < 128; ++j) acc += aa_embed[sel*128 + j] * m0[(256+j)*128 + t];
    if (f) {
      float cacc = 0.f;
      #pragma unroll 4
      for (int j = 0; j < 128; ++j) cacc += gb2[j] * m0[(128+j)*128 + t];
      acc += 8.0f * RS8 * cacc;
    }
    ((float*)(ws + AAW_OFF))[sf*128 + t] = acc;
  }
}

// ------- prep2 (AFTER scatter): EW1 -> CUR region, TW1 = T@W1 in place -------
__global__ void k_prep2(const float* atom_embed, const float* g1, const float* gb1,
                        char* ws) {
  int b = blockIdx.x, t = threadIdx.x;
  float s0 = 0.f, s1 = 0.f, s2 = 0.f, s3 = 0.f;
  const float* row = (b < 100) ? (atom_embed + b*128) : ((float*)(ws + T_OFF) + (b-100)*128);
  #pragma unroll 4
  for (int k = 0; k < 128; k += 4) {
    s0 += row[k+0] * g1[(k+0)*128 + t];
    s1 += row[k+1] * g1[(k+1)*128 + t];
    s2 += row[k+2] * g1[(k+2)*128 + t];
    s3 += row[k+3] * g1[(k+3)*128 + t];
  }
  float s = (s0 + s1) + (s2 + s3);
  if (b < 100) {
    ((float*)(ws + CUR_OFF))[b*128 + t] = s + gb1[t];
  } else {
    __syncthreads();
    ((float*)(ws + T_OFF))[(b-100)*128 + t] = s;
  }
}

// ---------------- count: 4 edges/thread, int4-vectorized ----------------
__global__ void k_count4(const int* __restrict__ bonds, char* ws) {
  int base = (blockIdx.x*256 + threadIdx.x)*4;
  if (base >= NEDGE) return;
  const unsigned char* gm = (const unsigned char*)(ws + GM_OFF);
  const int4* bp = (const int4*)(bonds + base*3);
  int4 w0 = bp[0], w1 = bp[1], w2 = bp[2];
  int srcs[4] = {w0.x, w0.w, w1.z, w2.y};
  int dsts[4] = {w0.y, w1.x, w1.w, w2.z};
  #pragma unroll
  for (int i = 0; i < 4; ++i) {
    if (gm[srcs[i] >> 3] | gm[dsts[i] >> 3]) continue;
    atomicAdd((int*)(ws + START_OFF) + dsts[i], 1);
  }
}

// ---------------- exclusive scan over 400000 counts ----------------
__global__ void k_scan1(char* ws) {
  __shared__ int s[256];
  int b = blockIdx.x, t = threadIdx.x, i = b*256 + t;
  int* cnt = (int*)(ws + START_OFF);
  int v = (i < NATOM) ? cnt[i] : 0;
  s[t] = v; __syncthreads();
  for (int d = 1; d < 256; d <<= 1) {
    int x = (t >= d) ? s[t-d] : 0;
    __syncthreads(); s[t] += x; __syncthreads();
  }
  if (i < NATOM) cnt[i] = s[t] - v;
  if (t == 255) ((int*)(ws + BS_OFF))[b] = s[255];
}
__global__ void k_scan2(char* ws) {
  __shared__ int s[256]; __shared__ int carry;
  int t = threadIdx.x;
  int* bs = (int*)(ws + BS_OFF);
  if (t == 0) carry = 0;
  __syncthreads();
  for (int c = 0; c < 7; ++c) {
    int i = c*256 + t;
    int v = (i < NBS) ? bs[i] : 0;
    s[t] = v; __syncthreads();
    for (int d = 1; d < 256; d <<= 1) {
      int x = (t >= d) ? s[t-d] : 0;
      __syncthreads(); s[t] += x; __syncthreads();
    }
    int excl = s[t] - v + carry;
    if (i < NBS) bs[i] = excl;
    int tot = s[255]; __syncthreads();
    if (t == 0) carry += tot;
    __syncthreads();
  }
  if (t == 0) ((int*)(ws + START_OFF))[NATOM] = carry;
}
__global__ void k_scan3(char* ws) {
  int b = blockIdx.x, i = b*256 + threadIdx.x;
  if (i >= NATOM) return;
  int* start = (int*)(ws + START_OFF);
  int v = start[i] + ((int*)(ws + BS_OFF))[b];
  start[i] = v;
  ((int*)(ws + CUR_OFF))[i] = v;
}

// ---------------- scatter: 4 edges/thread ----------------
__global__ void k_scatter4(const int* __restrict__ bonds, const int* __restrict__ A, char* ws) {
  int base = (blockIdx.x*256 + threadIdx.x)*4;
  if (base >= NEDGE) return;
  const unsigned char* gm = (const unsigned char*)(ws + GM_OFF);
  const int4* bp = (const int4*)(bonds + base*3);
  int4 w0 = bp[0], w1 = bp[1], w2 = bp[2];
  int srcs[4] = {w0.x, w0.w, w1.z, w2.y};
  int dsts[4] = {w0.y, w1.x, w1.w, w2.z};
  int bts[4]  = {w0.z, w1.y, w2.x, w2.w};
  #pragma unroll
  for (int i = 0; i < 4; ++i) {
    if (gm[srcs[i] >> 3] | gm[dsts[i] >> 3]) continue;
    int slot = atomicAdd((int*)(ws + CUR_OFF) + dsts[i], 1);
    if (slot >= 0 && slot < NEDGE)
      ((unsigned short*)(ws + REC_OFF))[slot] = (unsigned short)(A[srcs[i]]*5 + bts[i]);
  }
}

// ---- gather (r8-proven shape): per atom u = relu(EW1[A]+sum TW1); sum_8 -> topo_pre ----
__launch_bounds__(256, 6)
__global__ void k_gather(char* ws, const int* __restrict__ A) {
  __shared__ __align__(16) char sm[16384];
  const int tid = threadIdx.x;
  const int row0 = blockIdx.x * 64;                 // atom base
  const unsigned char* gm = (const unsigned char*)(ws + GM_OFF);

  {
    const int rowL = tid >> 2, q = tid & 3;
    const int atom = row0 + rowL;
    float u[32];
    #pragma unroll
    for (int k = 0; k < 32; ++k) u[k] = 0.f;
    if (!gm[atom >> 3]) {
      const int* start = (const int*)(ws + START_OFF);
      const unsigned short* rec = (const unsigned short*)(ws + REC_OFF);
      const float* EW1 = (const float*)(ws + CUR_OFF);
      const float* TW1 = (const float*)(ws + T_OFF);
      int aT = A[atom];
      const f32x4* ep = (const f32x4*)(EW1 + aT*128 + q*32);
      #pragma unroll
      for (int j = 0; j < 8; ++j) {
        f32x4 t = ep[j];
        #pragma unroll
        for (int k = 0; k < 4; ++k) u[j*4+k] = t[k];
      }
      int s0 = start[atom], s1 = start[atom+1];
      if (s0 < 0) s0 = 0;
      if (s1 > NEDGE) s1 = NEDGE;
      for (int s = s0; s < s1; ++s) {
        int p = rec[s];
        if (p >= 500) p = 0;
        const f32x4* tp = (const f32x4*)(TW1 + p*128 + q*32);
        #pragma unroll
        for (int j = 0; j < 8; ++j) {
          f32x4 t = tp[j];
          #pragma unroll
          for (int k = 0; k < 4; ++k) u[j*4+k] += t[k];
        }
      }
    }
    #pragma unroll
    for (int j = 0; j < 4; ++j) {
      bf16x8 o;
      #pragma unroll
      for (int k = 0; k < 8; ++k) o[k] = (__bf16)fmaxf(u[j*8+k], 0.f);
      int byte = rowL*256 + (((q*64) + j*16) ^ ((rowL & 7) << 4));
      *(bf16x8*)(sm + byte) = o;
    }
  }
  __syncthreads();

  {
    const int ml = tid >> 5, cs = tid & 31;
    const int mol = (row0 >> 3) + ml;
    float s0 = 0.f, s1 = 0.f, s2 = 0.f, s3 = 0.f;
    #pragma unroll
    for (int r = 0; r < 8; ++r) {
      int row = ml*8 + r;
      int byte = row*256 + ((cs*8) ^ ((row & 7) << 4));
      bf16x4 v = *(const bf16x4*)(sm + byte);
      s0 += (float)v[0]; s1 += (float)v[1]; s2 += (float)v[2]; s3 += (float)v[3];
    }
    bf16x4 o;
    o[0] = (__bf16)s0; o[1] = (__bf16)s1; o[2] = (__bf16)s2; o[3] = (__bf16)s3;
    *(bf16x4*)((char*)ws + TOPO_OFF + (long)mol*256 + cs*8) = o;
  }
}

// ------------- GEMM core: 64x128 tile, 4 waves, K=128, single LDS panel -------------
__device__ inline void gemm4(const char* sm, int aoff, const __bf16* wt,
                             const float* bias, int lane, int wave, f32x4 acc[4][2]) {
  const int colA = wave*32 + (lane & 15);
  const int k0   = (lane >> 4) * 8;
  float bb0 = bias[colA], bb1 = bias[colA + 16];
  #pragma unroll
  for (int m = 0; m < 4; ++m) { acc[m][0] = splat4(bb0); acc[m][1] = splat4(bb1); }
  #pragma unroll
  for (int kb = 0; kb < 4; ++kb) {
    bf16x8 b0 = *(const bf16x8*)(wt + colA*128 + kb*32 + k0);
    bf16x8 b1 = *(const bf16x8*)(wt + (colA+16)*128 + kb*32 + k0);
    #pragma unroll
    for (int m = 0; m < 4; ++m) {
      int rA = m*16 + (lane & 15);
      int byte = aoff + rA*256 + (((kb*64) + k0*2) ^ ((rA & 7) << 4));
      bf16x8 a = *(const bf16x8*)(sm + byte);
      acc[m][0] = MFMA(a, b0, acc[m][0]);
      acc[m][1] = MFMA(a, b1, acc[m][1]);
    }
  }
}

__device__ inline void stor4(char* sm, int off, f32x4 acc[4][2],
                             int lane, int wave, bool do_relu) {
  #pragma unroll
  for (int m = 0; m < 4; ++m)
  #pragma unroll
  for (int nf = 0; nf < 2; ++nf)
  #pragma unroll
  for (int r = 0; r < 4; ++r) {
    float v = acc[m][nf][r];
    if (do_relu && v < 0.f) v = 0.f;
    int row = m*16 + (lane >> 4)*4 + r;
    int col = wave*32 + nf*16 + (lane & 15);
    int byte = off + row*256 + ((col*2) ^ ((row & 7) << 4));
    *(__bf16*)(sm + byte) = (__bf16)v;
  }
}

// ---- mlp3: stage topo_pre -> GEMM_T(K=128)+epilogue(PW/AAW adds) -> GEMM1 -> GEMM3 ----
// LDS 32768: topo/h1 @0 (16K); h2+scalars @16384 (16K). 5 blocks/CU.
__launch_bounds__(256)
__global__ void k_mlp3(char* ws, const int* __restrict__ pos_ids,
                       const int* __restrict__ is_aa, const float* cr,
                       const float* mb0, const float* mb1, const float* mb2,
                       float* __restrict__ out) {
  __shared__ __align__(16) char sm[32768];
  const int tid = threadIdx.x, lane = tid & 63, wave = tid >> 6;
  const int r0 = blockIdx.x * 64;
  const unsigned char* gm = (const unsigned char*)(ws + GM_OFF);
  const __bf16* topo_pre = (const __bf16*)(ws + TOPO_OFF);

  // stage topo panel @0: 1024 chunks of 16B
  for (int i = 0; i < 4; ++i) {
    int idx = tid + i*256;
    int row = idx >> 4, c = idx & 15;
    int mol = r0 + row;
    bf16x8 v;
    #pragma unroll
    for (int j = 0; j < 8; ++j) v[j] = (__bf16)0.f;
    if (mol < NBLK) v = *(const bf16x8*)(topo_pre + (long)mol*128 + c*8);
    int byte = row*256 + ((c*16) ^ ((row & 7) << 4));
    *(bf16x8*)(sm + byte) = v;
  }
  // per-row scalars: packed = pid | sel<<12 | f<<13  -> @16384
  if (tid < 64) {
    int mol = r0 + tid, packed = 0;
    if (mol < NBLK) {
      int g = gm[mol];
      int corrupt = g && (cr[mol] < 0.1f);
      int sel = corrupt ? 0 : is_aa[mol];
      packed = pos_ids[mol] | (sel << 12) | ((g ? 0 : 1) << 13);
    }
    *(int*)(sm + 16384 + tid*4) = packed;
  }
  __syncthreads();                                       // B0

  f32x4 acc[4][2];
  // GEMM_T: topo_pre @ W2T' + b0  (the W2 and W0-topo GEMMs, merged)
  gemm4(sm, 0, (const __bf16*)(ws + W2T_OFF), mb0, lane, wave, acc);
  // epilogue: + PW[pid] + AAW[sel+2f], relu  -> h1 in acc
  {
    const __bf16* PW = (const __bf16*)(ws + PW_OFF);
    const float* AAW = (const float*)(ws + AAW_OFF);
    #pragma unroll
    for (int m = 0; m < 4; ++m)
    #pragma unroll
    for (int r = 0; r < 4; ++r) {
      int row = m*16 + (lane >> 4)*4 + r;
      int packed = *(const int*)(sm + 16384 + row*4);
      int pid = packed & 0xFFF, sf = (packed >> 12) & 3;
      #pragma unroll
      for (int nf = 0; nf < 2; ++nf) {
        int col = wave*32 + nf*16 + (lane & 15);
        float v = acc[m][nf][r] + (float)PW[pid*128 + col] + AAW[sf*128 + col];
        acc[m][nf][r] = fmaxf(v, 0.f);
      }
    }
  }
  __syncthreads();                                       // B1: topo reads + scalar reads done
  stor4(sm, 0, acc, lane, wave, false);                  // h1 over topo panel
  __syncthreads();                                       // B2

  gemm4(sm, 0, (const __bf16*)(ws + M1T_OFF), mb1, lane, wave, acc);
  stor4(sm, 16384, acc, lane, wave, true);               // h2 (clobbers scalars: consumed)
  __syncthreads();                                       // B3

  gemm4(sm, 16384, (const __bf16*)(ws + M2T_OFF), mb2, lane, wave, acc);
  #pragma unroll
  for (int m = 0; m < 4; ++m)
  #pragma unroll
  for (int nf = 0; nf < 2; ++nf)
  #pragma unroll
  for (int r = 0; r < 4; ++r) {
    int row = m*16 + (lane >> 4)*4 + r;
    int col = wave*32 + nf*16 + (lane & 15);
    int mol = r0 + row;
    if (mol < NBLK) out[(long)mol*128 + col] = scrub(acc[m][nf][r]);
  }
}

extern "C" void kernel_launch(void* const* d_in, const int* in_sizes, int n_in,
                              void* d_out, int out_size, void* d_ws, size_t ws_size,
                              hipStream_t stream) {
  if (ws_size < WS_NEED) return;   // diagnostic: absmax-fail instead of fault
  const int* A      = (const int*)d_in[0];
  const int* bonds  = (const int*)d_in[1];
  const void* gm    = d_in[3];
  const int* pos    = (const int*)d_in[4];
  const int* isaa   = (const int*)d_in[5];
  const float* cr   = (const float*)d_in[6];
  const float* atom_embed = (const float*)d_in[7];
  const float* bond_embed = (const float*)d_in[8];
  const float* aa_embed   = (const float*)d_in[9];
  const float* g1  = (const float*)d_in[10];
  const float* gb1 = (const float*)d_in[11];
  const float* g2  = (const float*)d_in[12];
  const float* gb2 = (const float*)d_in[13];
  const float* m0  = (const float*)d_in[14];
  const float* mb0 = (const float*)d_in[15];
  const float* m1  = (const float*)d_in[16];
  const float* mb1 = (const float*)d_in[17];
  const float* m2  = (const float*)d_in[18];
  const float* mb2 = (const float*)d_in[19];
  char* ws = (char*)d_ws;

  hipMemsetAsync(ws + START_OFF, 0, (size_t)(NATOM+1)*4, stream);
  k_sniff   <<<1, 256, 0, stream>>>(gm, ws);
  k_prep1   <<<166, 128, 0, stream>>>(atom_embed, bond_embed, m1, m2, gm, ws);
  k_prep3   <<<1156, 128, 0, stream>>>(m0, g2, gb2, aa_embed, ws);
  k_count4  <<<782, 256, 0, stream>>>(bonds, ws);
  k_scan1   <<<NBS, 256, 0, stream>>>(ws);
  k_scan2   <<<1, 256, 0, stream>>>(ws);
  k_scan3   <<<NBS, 256, 0, stream>>>(ws);
  k_scatter4<<<782, 256, 0, stream>>>(bonds, A, ws);
  k_prep2   <<<600, 128, 0, stream>>>(atom_embed, g1, gb1, ws);   // EW1 -> CUR, TW1 in place
  k_gather  <<<NATOM/64, 256, 0, stream>>>(ws, A);
  k_mlp3    <<<(NBLK + 63)/64, 256, 0, stream>>>(ws, pos, isaa, cr,
                                                 mb0, mb1, mb2, (float*)d_out);
}